// Round 1
// baseline (2616.806 us; speedup 1.0000x reference)
//
#include <hip/hip_runtime.h>
#include <math.h>

#define NUM_USER 150000
#define NUM_ITEM 75000
#define N_TOTAL  225000
#define D        64
#define LAYERS   3
#define SCALE    0.01f

// bucket geometry: 128 rows per bucket
#define BROWS    128
#define BSHIFT   7
#define NBUCK    1758            // ceil(225000 / 128)
#define COLBITS  18
#define COLMASK  0x3FFFF         // N_TOTAL = 225000 < 2^18
#define CHUNK    16384           // edges per binscatter block

// ---------------------------------------------------------------------------
// zero int buffer
// ---------------------------------------------------------------------------
__global__ void k_zero(int* __restrict__ p, int n) {
    for (int i = blockIdx.x * blockDim.x + threadIdx.x; i < n;
         i += gridDim.x * blockDim.x)
        p[i] = 0;
}

// ---------------------------------------------------------------------------
// bucket histogram: LDS-staged, one global atomic per (block,bucket)
// ---------------------------------------------------------------------------
__global__ __launch_bounds__(256) void k_binhist(const int* __restrict__ rows,
                                                 int* __restrict__ bcnt, int nnz) {
    __shared__ int h[NBUCK];
    const int tid = threadIdx.x;
    for (int i = tid; i < NBUCK; i += 256) h[i] = 0;
    __syncthreads();
    for (int e = blockIdx.x * blockDim.x + tid; e < nnz;
         e += gridDim.x * blockDim.x)
        atomicAdd(&h[rows[e] >> BSHIFT], 1);
    __syncthreads();
    for (int i = tid; i < NBUCK; i += 256)
        if (h[i]) atomicAdd(&bcnt[i], h[i]);
}

// ---------------------------------------------------------------------------
// single-block exclusive scan of bucket counts -> boff, bcur (NBUCK <= 2048)
// ---------------------------------------------------------------------------
__global__ __launch_bounds__(256) void k_bscan(const int* __restrict__ bcnt,
                                               int* __restrict__ boff,
                                               int* __restrict__ bcur,
                                               int n, int nnz) {
    __shared__ int sd[256];
    const int t = threadIdx.x;
    const int base = t * 8;
    int v[8], s = 0;
#pragma unroll
    for (int i = 0; i < 8; ++i) {
        int idx = base + i;
        v[i] = (idx < n) ? bcnt[idx] : 0;
        s += v[i];
    }
    sd[t] = s;
    __syncthreads();
#pragma unroll
    for (int o = 1; o < 256; o <<= 1) {
        int x = (t >= o) ? sd[t - o] : 0;
        __syncthreads();
        if (t >= o) sd[t] += x;
        __syncthreads();
    }
    int run = (t == 0) ? 0 : sd[t - 1];
#pragma unroll
    for (int i = 0; i < 8; ++i) {
        int idx = base + i;
        if (idx < n) { boff[idx] = run; bcur[idx] = run; }
        run += v[i];
    }
    if (t == 255) boff[n] = nnz;
}

// ---------------------------------------------------------------------------
// bin edges into bucket-contiguous packed records.
// record = { (row_local << 18) | col , bits(val) }  -- one 8B store per edge
// per-block run reservation makes writes land in ~75B contiguous runs.
// ---------------------------------------------------------------------------
__global__ __launch_bounds__(256) void k_binscatter(
        const int* __restrict__ rows, const int* __restrict__ cols,
        const float* __restrict__ vals, int* __restrict__ bcur,
        uint2* __restrict__ rec, int nnz) {
    __shared__ int hist[NBUCK];
    __shared__ int runs[NBUCK];
    const int tid = threadIdx.x;
    const int e0 = blockIdx.x * CHUNK;
    const int e1 = min(nnz, e0 + CHUNK);

    for (int i = tid; i < NBUCK; i += 256) hist[i] = 0;
    __syncthreads();
    // pass 1: count
    for (int e = e0 + tid; e < e1; e += 256)
        atomicAdd(&hist[rows[e] >> BSHIFT], 1);
    __syncthreads();
    // reserve runs
    for (int i = tid; i < NBUCK; i += 256)
        runs[i] = hist[i] ? atomicAdd(&bcur[i], hist[i]) : 0;
    __syncthreads();
    // reset hist -> local cursors
    for (int i = tid; i < NBUCK; i += 256) hist[i] = 0;
    __syncthreads();
    // pass 2: place
    for (int e = e0 + tid; e < e1; e += 256) {
        const int r = rows[e];
        const int b = r >> BSHIFT;
        const int pos = runs[b] + atomicAdd(&hist[b], 1);
        const unsigned key = ((unsigned)(r & (BROWS - 1)) << COLBITS) |
                             (unsigned)cols[e];
        rec[pos] = make_uint2(key, __float_as_uint(vals[e]));
    }
}

// ---------------------------------------------------------------------------
// bucketed SpMM: one block per 128-row bucket, 128x64 f32 accumulator in LDS.
// lane = dim, shfl-broadcast of packed records, ds_add accumulate.
// MODE 0: first layer  (gather ue/ie,  acc  = y, write y)
// MODE 1: mid layer    (gather xbuf,   acc += y, write y)
// MODE 2: last layer   (gather xbuf,   acc += y, skip y write)
// ---------------------------------------------------------------------------
template <int MODE>
__global__ __launch_bounds__(512) void k_spmm_b(
        const int* __restrict__ boff, const uint2* __restrict__ rec,
        const float* __restrict__ ue, const float* __restrict__ ie,
        const float* __restrict__ xbuf,
        float* __restrict__ ybuf, float* __restrict__ accbuf) {
    __shared__ float lacc[BROWS * D];      // 32 KB -> 4 blocks/CU
    const int tid = threadIdx.x;
    float4* l4 = (float4*)lacc;
    for (int i = tid; i < BROWS * D / 4; i += 512)
        l4[i] = make_float4(0.f, 0.f, 0.f, 0.f);
    __syncthreads();

    const int b    = blockIdx.x;
    const int lane = tid & 63;
    const int wid  = tid >> 6;
    const int s = boff[b];
    const int e = boff[b + 1];

    for (int base = s + wid * 64; base < e; base += 512) {
        const int nv = min(64, e - base);
        uint2 rv = make_uint2(0u, 0u);
        if (lane < nv) rv = rec[base + lane];
        int j = 0;
        for (; j + 4 <= nv; j += 4) {
            unsigned k0 = __shfl(rv.x, j),     k1 = __shfl(rv.x, j + 1);
            unsigned k2 = __shfl(rv.x, j + 2), k3 = __shfl(rv.x, j + 3);
            unsigned w0 = __shfl(rv.y, j),     w1 = __shfl(rv.y, j + 1);
            unsigned w2 = __shfl(rv.y, j + 2), w3 = __shfl(rv.y, j + 3);
            const int c0 = k0 & COLMASK, c1 = k1 & COLMASK;
            const int c2 = k2 & COLMASK, c3 = k3 & COLMASK;
            const float v0 = __uint_as_float(w0), v1 = __uint_as_float(w1);
            const float v2 = __uint_as_float(w2), v3 = __uint_as_float(w3);
            float x0, x1, x2, x3;
            if (MODE == 0) {
                x0 = (c0 < NUM_USER) ? ue[c0 * D + lane] : ie[(c0 - NUM_USER) * D + lane];
                x1 = (c1 < NUM_USER) ? ue[c1 * D + lane] : ie[(c1 - NUM_USER) * D + lane];
                x2 = (c2 < NUM_USER) ? ue[c2 * D + lane] : ie[(c2 - NUM_USER) * D + lane];
                x3 = (c3 < NUM_USER) ? ue[c3 * D + lane] : ie[(c3 - NUM_USER) * D + lane];
            } else {
                x0 = xbuf[c0 * D + lane]; x1 = xbuf[c1 * D + lane];
                x2 = xbuf[c2 * D + lane]; x3 = xbuf[c3 * D + lane];
            }
            atomicAdd(&lacc[((k0 >> COLBITS) << 6) + lane], v0 * x0);
            atomicAdd(&lacc[((k1 >> COLBITS) << 6) + lane], v1 * x1);
            atomicAdd(&lacc[((k2 >> COLBITS) << 6) + lane], v2 * x2);
            atomicAdd(&lacc[((k3 >> COLBITS) << 6) + lane], v3 * x3);
        }
        for (; j < nv; ++j) {
            unsigned k = __shfl(rv.x, j);
            unsigned w = __shfl(rv.y, j);
            const int c = k & COLMASK;
            const float v = __uint_as_float(w);
            float x;
            if (MODE == 0)
                x = (c < NUM_USER) ? ue[c * D + lane] : ie[(c - NUM_USER) * D + lane];
            else
                x = xbuf[c * D + lane];
            atomicAdd(&lacc[((k >> COLBITS) << 6) + lane], v * x);
        }
    }
    __syncthreads();

    // coalesced write-out
    const int r0 = b * BROWS;
    const int nr = min(BROWS, N_TOTAL - r0);
    float4* acc4 = (float4*)accbuf;
    float4* y4   = (float4*)ybuf;
    for (int idx = tid; idx < nr * (D / 4); idx += 512) {
        float4 v = l4[idx];
        const size_t o = (size_t)r0 * (D / 4) + idx;
        if (MODE == 0) {
            acc4[o] = v;
            y4[o] = v;
        } else if (MODE == 1) {
            float4 a = acc4[o];
            a.x += v.x; a.y += v.y; a.z += v.z; a.w += v.w;
            acc4[o] = a;
            y4[o] = v;
        } else {
            float4 a = acc4[o];
            a.x += v.x; a.y += v.y; a.z += v.z; a.w += v.w;
            acc4[o] = a;
        }
    }
}

// ---------------------------------------------------------------------------
// final: mean = acc/3; logstd = mean @ W + b; std = exp; views
// ---------------------------------------------------------------------------
__global__ __launch_bounds__(256) void k_final(
        float* __restrict__ mean_io,
        const float* __restrict__ W, const float* __restrict__ bias,
        const float* __restrict__ n1, const float* __restrict__ n2,
        float* __restrict__ std_out, float* __restrict__ v1,
        float* __restrict__ v2, int nrows) {
    __shared__ float Wl[64 * 64];
    __shared__ float rowbuf[4][64];
    for (int i = threadIdx.x; i < 64 * 64; i += blockDim.x) Wl[i] = W[i];
    __syncthreads();

    const int   lane = threadIdx.x & 63;
    const int   wv   = threadIdx.x >> 6;
    const float bj   = bias[lane];
    const int   w0   = blockIdx.x * 4 + wv;
    const int   nw   = gridDim.x * 4;

    for (int r = w0; r < nrows; r += nw) {
        const size_t base = (size_t)r * D;
        float m = mean_io[base + lane] * (1.f / 3.f);
        rowbuf[wv][lane] = m;
        float s = bj;
#pragma unroll
        for (int k = 0; k < 64; ++k)
            s = fmaf(rowbuf[wv][k], Wl[k * 64 + lane], s);
        float sd = __expf(s);
        mean_io[base + lane] = m;
        std_out[base + lane] = sd;
        v1[base + lane] = fmaf(sd * SCALE, n1[base + lane], m);
        v2[base + lane] = fmaf(sd * SCALE, n2[base + lane], m);
    }
}

// ---------------------------------------------------------------------------
extern "C" void kernel_launch(void* const* d_in, const int* in_sizes, int n_in,
                              void* d_out, int out_size, void* d_ws, size_t ws_size,
                              hipStream_t stream) {
    const float* ue   = (const float*)d_in[0];
    const float* ie   = (const float*)d_in[1];
    const float* W    = (const float*)d_in[2];
    const float* bias = (const float*)d_in[3];
    const int*   rows = (const int*)d_in[4];
    const int*   cols = (const int*)d_in[5];
    const float* vals = (const float*)d_in[6];
    const float* n1   = (const float*)d_in[7];
    const float* n2   = (const float*)d_in[8];
    const int    nnz  = in_sizes[4];

    float* out = (float*)d_out;
    const size_t ND = (size_t)N_TOTAL * D;

    // d_out layout: [mean | std | view1 | view2]
    // std segment doubles as binning scratch until k_final; view segs = ego ping-pong.
    float* acc  = out;            // mean segment: layer accumulator -> mean
    float* stdo = out + ND;       // std segment: scratch now, std at end
    float* y1   = out + 2 * ND;   // view1 segment: ego after layer 1
    float* y2   = out + 3 * ND;   // view2 segment: ego after layer 2

    // scratch carved from std segment (needs 32KB + 16MB of 57.6MB)
    int*   ws   = (int*)stdo;
    int*   bcnt = ws;                          // NBUCK
    int*   boff = ws + 2048;                   // NBUCK+1
    int*   bcur = ws + 4096;                   // NBUCK
    uint2* rec  = (uint2*)(ws + 8192);         // nnz packed records (16MB)

    const int nb2 = (nnz + CHUNK - 1) / CHUNK;

    // --- bucket-bin the edges (re-built every call; inputs re-poisoned) ---
    k_zero<<<7, 256, 0, stream>>>(bcnt, NBUCK);
    k_binhist<<<256, 256, 0, stream>>>(rows, bcnt, nnz);
    k_bscan<<<1, 256, 0, stream>>>(bcnt, boff, bcur, NBUCK, nnz);
    k_binscatter<<<nb2, 256, 0, stream>>>(rows, cols, vals, bcur, rec, nnz);

    // --- 3 GCN layers, LDS-accumulated per bucket ---
    k_spmm_b<0><<<NBUCK, 512, 0, stream>>>(boff, rec, ue, ie, nullptr, y1, acc);
    k_spmm_b<1><<<NBUCK, 512, 0, stream>>>(boff, rec, nullptr, nullptr, y1, y2, acc);
    k_spmm_b<2><<<NBUCK, 512, 0, stream>>>(boff, rec, nullptr, nullptr, y2, nullptr, acc);

    // --- epilogue (overwrites all four output segments) ---
    k_final<<<2048, 256, 0, stream>>>(acc, W, bias, n1, n2,
                                      stdo, y1, y2, N_TOTAL);
}

// Round 2
// 749.651 us; speedup vs baseline: 3.4907x; 3.4907x over previous
//
#include <hip/hip_runtime.h>
#include <math.h>

#define NUM_USER 150000
#define NUM_ITEM 75000
#define N_TOTAL  225000
#define D        64
#define LAYERS   3
#define SCALE    0.01f

// bucket geometry: 128 rows per bucket
#define BROWS    128
#define BSHIFT   7
#define NBUCK    1758            // ceil(225000 / 128)
#define COLBITS  18
#define COLMASK  0x3FFFF         // N_TOTAL = 225000 < 2^18
#define CHUNK    8192            // edges per binscatter block (245 blocks)

// ---------------------------------------------------------------------------
// zero int buffer
// ---------------------------------------------------------------------------
__global__ void k_zero(int* __restrict__ p, int n) {
    for (int i = blockIdx.x * blockDim.x + threadIdx.x; i < n;
         i += gridDim.x * blockDim.x)
        p[i] = 0;
}

// ---------------------------------------------------------------------------
// bucket histogram: LDS-staged (int atomics = native), one global atomic
// per (block,bucket)
// ---------------------------------------------------------------------------
__global__ __launch_bounds__(256) void k_binhist(const int* __restrict__ rows,
                                                 int* __restrict__ bcnt, int nnz) {
    __shared__ int h[NBUCK];
    const int tid = threadIdx.x;
    for (int i = tid; i < NBUCK; i += 256) h[i] = 0;
    __syncthreads();
    for (int e = blockIdx.x * blockDim.x + tid; e < nnz;
         e += gridDim.x * blockDim.x)
        atomicAdd(&h[rows[e] >> BSHIFT], 1);
    __syncthreads();
    for (int i = tid; i < NBUCK; i += 256)
        if (h[i]) atomicAdd(&bcnt[i], h[i]);
}

// ---------------------------------------------------------------------------
// single-block exclusive scan of bucket counts -> boff, bcur (NBUCK <= 2048)
// ---------------------------------------------------------------------------
__global__ __launch_bounds__(256) void k_bscan(const int* __restrict__ bcnt,
                                               int* __restrict__ boff,
                                               int* __restrict__ bcur,
                                               int n, int nnz) {
    __shared__ int sd[256];
    const int t = threadIdx.x;
    const int base = t * 8;
    int v[8], s = 0;
#pragma unroll
    for (int i = 0; i < 8; ++i) {
        int idx = base + i;
        v[i] = (idx < n) ? bcnt[idx] : 0;
        s += v[i];
    }
    sd[t] = s;
    __syncthreads();
#pragma unroll
    for (int o = 1; o < 256; o <<= 1) {
        int x = (t >= o) ? sd[t - o] : 0;
        __syncthreads();
        if (t >= o) sd[t] += x;
        __syncthreads();
    }
    int run = (t == 0) ? 0 : sd[t - 1];
#pragma unroll
    for (int i = 0; i < 8; ++i) {
        int idx = base + i;
        if (idx < n) { boff[idx] = run; bcur[idx] = run; }
        run += v[i];
    }
    if (t == 255) boff[n] = nnz;
}

// ---------------------------------------------------------------------------
// bin edges into bucket-contiguous packed records.
// record = { (row_local << 18) | col , bits(val) }  -- one 8B store per edge
// per-block run reservation -> writes land in contiguous runs.
// ---------------------------------------------------------------------------
__global__ __launch_bounds__(256) void k_binscatter(
        const int* __restrict__ rows, const int* __restrict__ cols,
        const float* __restrict__ vals, int* __restrict__ bcur,
        uint2* __restrict__ rec, int nnz) {
    __shared__ int hist[NBUCK];
    __shared__ int runs[NBUCK];
    const int tid = threadIdx.x;
    const int e0 = blockIdx.x * CHUNK;
    const int e1 = min(nnz, e0 + CHUNK);

    for (int i = tid; i < NBUCK; i += 256) hist[i] = 0;
    __syncthreads();
    // pass 1: count
    for (int e = e0 + tid; e < e1; e += 256)
        atomicAdd(&hist[rows[e] >> BSHIFT], 1);
    __syncthreads();
    // reserve runs
    for (int i = tid; i < NBUCK; i += 256)
        runs[i] = hist[i] ? atomicAdd(&bcur[i], hist[i]) : 0;
    __syncthreads();
    // reset hist -> local cursors
    for (int i = tid; i < NBUCK; i += 256) hist[i] = 0;
    __syncthreads();
    // pass 2: place
    for (int e = e0 + tid; e < e1; e += 256) {
        const int r = rows[e];
        const int b = r >> BSHIFT;
        const int pos = runs[b] + atomicAdd(&hist[b], 1);
        const unsigned key = ((unsigned)(r & (BROWS - 1)) << COLBITS) |
                             (unsigned)cols[e];
        rec[pos] = make_uint2(key, __float_as_uint(vals[e]));
    }
}

// ---------------------------------------------------------------------------
// per-bucket counting sort: rec (bucket-contiguous) -> srec (row-sorted CSR
// order) + off[row].  One block per bucket; int LDS atomics only.  Scattered
// stores confined to the bucket's ~9 KB window => L2 merges, no amplification.
// ---------------------------------------------------------------------------
__global__ __launch_bounds__(256) void k_bsort(
        const int* __restrict__ boff, const uint2* __restrict__ rec,
        uint2* __restrict__ srec, int* __restrict__ off, int nnz) {
    __shared__ int h[BROWS];
    __shared__ int sc[BROWS];
    __shared__ int cur[BROWS];
    const int b = blockIdx.x;
    const int tid = threadIdx.x;
    const int s = boff[b];
    const int e = boff[b + 1];

    if (tid < BROWS) h[tid] = 0;
    __syncthreads();
    for (int i = s + tid; i < e; i += 256)
        atomicAdd(&h[rec[i].x >> COLBITS], 1);
    __syncthreads();
    if (tid < BROWS) sc[tid] = h[tid];
    __syncthreads();
#pragma unroll
    for (int o = 1; o < BROWS; o <<= 1) {
        int x = 0;
        if (tid < BROWS && tid >= o) x = sc[tid - o];
        __syncthreads();
        if (tid < BROWS && tid >= o) sc[tid] += x;
        __syncthreads();
    }
    const int r0 = b * BROWS;
    if (tid < BROWS) {
        const int excl = sc[tid] - h[tid];      // exclusive scan
        cur[tid] = excl;
        const int r = r0 + tid;
        if (r < N_TOTAL) off[r] = s + excl;
    }
    __syncthreads();
    for (int i = s + tid; i < e; i += 256) {
        const uint2 u = rec[i];
        const int rl = u.x >> COLBITS;
        const int p = s + atomicAdd(&cur[rl], 1);
        srec[p] = u;
    }
    if (b == 0 && tid == 0) off[N_TOTAL] = nnz;
}

// ---------------------------------------------------------------------------
// CSR SpMM, one wave per row, lane = dim, register accumulate.  No atomics.
// MODE 0: first layer  (gather from ue/ie, acc  = y, write y)
// MODE 1: mid layer    (gather from xbuf,  acc += y, write y)
// MODE 2: last layer   (gather from xbuf,  acc += y, skip y write)
// ---------------------------------------------------------------------------
template <int MODE>
__global__ __launch_bounds__(256) void k_spmm_csr(
        const int* __restrict__ off, const uint2* __restrict__ srec,
        const float* __restrict__ ue, const float* __restrict__ ie,
        const float* __restrict__ xbuf,
        float* __restrict__ ybuf, float* __restrict__ accbuf, int nrows) {
    const int lane = threadIdx.x & 63;
    const int w0   = (blockIdx.x * blockDim.x + threadIdx.x) >> 6;
    const int nw   = (gridDim.x * blockDim.x) >> 6;

    for (int r0 = w0; r0 < nrows; r0 += nw) {
        const int r = __builtin_amdgcn_readfirstlane(r0);
        const int s = off[r];
        const int e = off[r + 1];
        float accv = 0.f;
        for (int base = s; base < e; base += 64) {
            const int nv = min(64, e - base);
            uint2 rv = make_uint2(0u, 0u);
            if (lane < nv) rv = srec[base + lane];
            int j = 0;
            for (; j + 4 <= nv; j += 4) {
                unsigned k0 = __shfl(rv.x, j),     k1 = __shfl(rv.x, j + 1);
                unsigned k2 = __shfl(rv.x, j + 2), k3 = __shfl(rv.x, j + 3);
                unsigned w0_ = __shfl(rv.y, j),     w1_ = __shfl(rv.y, j + 1);
                unsigned w2_ = __shfl(rv.y, j + 2), w3_ = __shfl(rv.y, j + 3);
                const int c0 = k0 & COLMASK, c1 = k1 & COLMASK;
                const int c2 = k2 & COLMASK, c3 = k3 & COLMASK;
                const float v0 = __uint_as_float(w0_), v1 = __uint_as_float(w1_);
                const float v2 = __uint_as_float(w2_), v3 = __uint_as_float(w3_);
                float x0, x1, x2, x3;
                if (MODE == 0) {
                    x0 = (c0 < NUM_USER) ? ue[c0 * D + lane] : ie[(c0 - NUM_USER) * D + lane];
                    x1 = (c1 < NUM_USER) ? ue[c1 * D + lane] : ie[(c1 - NUM_USER) * D + lane];
                    x2 = (c2 < NUM_USER) ? ue[c2 * D + lane] : ie[(c2 - NUM_USER) * D + lane];
                    x3 = (c3 < NUM_USER) ? ue[c3 * D + lane] : ie[(c3 - NUM_USER) * D + lane];
                } else {
                    x0 = xbuf[c0 * D + lane]; x1 = xbuf[c1 * D + lane];
                    x2 = xbuf[c2 * D + lane]; x3 = xbuf[c3 * D + lane];
                }
                accv = fmaf(v0, x0, accv);
                accv = fmaf(v1, x1, accv);
                accv = fmaf(v2, x2, accv);
                accv = fmaf(v3, x3, accv);
            }
            for (; j < nv; ++j) {
                const unsigned k = __shfl(rv.x, j);
                const unsigned w = __shfl(rv.y, j);
                const int c = k & COLMASK;
                const float v = __uint_as_float(w);
                float x;
                if (MODE == 0)
                    x = (c < NUM_USER) ? ue[c * D + lane] : ie[(c - NUM_USER) * D + lane];
                else
                    x = xbuf[c * D + lane];
                accv = fmaf(v, x, accv);
            }
        }
        const int o = r * D + lane;
        if (MODE == 0) accbuf[o] = accv;
        else           accbuf[o] += accv;
        if (MODE != 2) ybuf[o] = accv;
    }
}

// ---------------------------------------------------------------------------
// final: mean = acc/3; logstd = mean @ W + b; std = exp; views.
// W column held in 64 VGPRs; row broadcast via v_readlane (no LDS inner loop).
// ---------------------------------------------------------------------------
__global__ __launch_bounds__(256) void k_final(
        float* __restrict__ mean_io,
        const float* __restrict__ W, const float* __restrict__ bias,
        const float* __restrict__ n1, const float* __restrict__ n2,
        float* __restrict__ std_out, float* __restrict__ v1,
        float* __restrict__ v2, int nrows) {
    const int   lane = threadIdx.x & 63;
    const float bj   = bias[lane];
    const int   w0   = (blockIdx.x * blockDim.x + threadIdx.x) >> 6;
    const int   nw   = (gridDim.x * blockDim.x) >> 6;

    float wreg[64];
#pragma unroll
    for (int k = 0; k < 64; ++k) wreg[k] = W[k * 64 + lane];

    for (int r = w0; r < nrows; r += nw) {
        const size_t base = (size_t)r * D;
        const float m = mean_io[base + lane] * (1.f / 3.f);
        float s = bj;
#pragma unroll
        for (int k = 0; k < 64; ++k) {
            const float mk = __uint_as_float(
                __builtin_amdgcn_readlane(__float_as_uint(m), k));
            s = fmaf(mk, wreg[k], s);
        }
        const float sd = __expf(s);
        mean_io[base + lane] = m;
        std_out[base + lane] = sd;
        v1[base + lane] = fmaf(sd * SCALE, n1[base + lane], m);
        v2[base + lane] = fmaf(sd * SCALE, n2[base + lane], m);
    }
}

// ---------------------------------------------------------------------------
extern "C" void kernel_launch(void* const* d_in, const int* in_sizes, int n_in,
                              void* d_out, int out_size, void* d_ws, size_t ws_size,
                              hipStream_t stream) {
    const float* ue   = (const float*)d_in[0];
    const float* ie   = (const float*)d_in[1];
    const float* W    = (const float*)d_in[2];
    const float* bias = (const float*)d_in[3];
    const int*   rows = (const int*)d_in[4];
    const int*   cols = (const int*)d_in[5];
    const float* vals = (const float*)d_in[6];
    const float* n1   = (const float*)d_in[7];
    const float* n2   = (const float*)d_in[8];
    const int    nnz  = in_sizes[4];

    float* out = (float*)d_out;
    const size_t ND = (size_t)N_TOTAL * D;

    // d_out layout: [mean | std | view1 | view2]
    // std segment doubles as binning scratch until k_final; view segs = ego ping-pong.
    float* acc  = out;            // mean segment: layer accumulator -> mean
    float* stdo = out + ND;       // std segment: scratch now, std at end
    float* y1   = out + 2 * ND;   // view1 segment: ego after layer 1
    float* y2   = out + 3 * ND;   // view2 segment: ego after layer 2

    // scratch carved from std segment (~33 MB of 57.6 MB)
    int*   ws   = (int*)stdo;
    int*   bcnt = ws;                          // NBUCK
    int*   boff = ws + 2048;                   // NBUCK+1
    int*   bcur = ws + 4096;                   // NBUCK
    int*   off  = ws + 6144;                   // N_TOTAL+1 (ends 231145)
    uint2* srec = (uint2*)(ws + 231424);       // nnz sorted records (16 MB)
    uint2* rec  = (uint2*)(ws + 4231424);      // nnz bucket-binned records (16 MB)

    const int nb2 = (nnz + CHUNK - 1) / CHUNK;

    // --- two-level CSR build: bucket-bin (coalesced) then in-bucket sort ---
    k_zero<<<7, 256, 0, stream>>>(bcnt, NBUCK);
    k_binhist<<<256, 256, 0, stream>>>(rows, bcnt, nnz);
    k_bscan<<<1, 256, 0, stream>>>(bcnt, boff, bcur, NBUCK, nnz);
    k_binscatter<<<nb2, 256, 0, stream>>>(rows, cols, vals, bcur, rec, nnz);
    k_bsort<<<NBUCK, 256, 0, stream>>>(boff, rec, srec, off, nnz);

    // --- 3 GCN layers, row-per-wave CSR, register accumulate ---
    k_spmm_csr<0><<<2048, 256, 0, stream>>>(off, srec, ue, ie, nullptr,
                                            y1, acc, N_TOTAL);
    k_spmm_csr<1><<<2048, 256, 0, stream>>>(off, srec, nullptr, nullptr, y1,
                                            y2, acc, N_TOTAL);
    k_spmm_csr<2><<<2048, 256, 0, stream>>>(off, srec, nullptr, nullptr, y2,
                                            nullptr, acc, N_TOTAL);

    // --- epilogue (overwrites all four output segments) ---
    k_final<<<2048, 256, 0, stream>>>(acc, W, bias, n1, n2,
                                      stdo, y1, y2, N_TOTAL);
}

// Round 3
// 717.399 us; speedup vs baseline: 3.6476x; 1.0450x over previous
//
#include <hip/hip_runtime.h>
#include <math.h>

#define NUM_USER 150000
#define NUM_ITEM 75000
#define N_TOTAL  225000
#define D        64
#define LAYERS   3
#define SCALE    0.01f

// bucket geometry: 128 rows per bucket
#define BROWS    128
#define BSHIFT   7
#define NBUCK    1758            // ceil(225000 / 128)
#define COLBITS  18
#define COLMASK  0x3FFFF         // N_TOTAL = 225000 < 2^18
#define CHUNK    8192            // edges per binscatter block (245 blocks)

// ---------------------------------------------------------------------------
// zero int buffer
// ---------------------------------------------------------------------------
__global__ void k_zero(int* __restrict__ p, int n) {
    for (int i = blockIdx.x * blockDim.x + threadIdx.x; i < n;
         i += gridDim.x * blockDim.x)
        p[i] = 0;
}

// ---------------------------------------------------------------------------
// bucket histogram: LDS-staged (int atomics = native), one global atomic
// per (block,bucket)
// ---------------------------------------------------------------------------
__global__ __launch_bounds__(256) void k_binhist(const int* __restrict__ rows,
                                                 int* __restrict__ bcnt, int nnz) {
    __shared__ int h[NBUCK];
    const int tid = threadIdx.x;
    for (int i = tid; i < NBUCK; i += 256) h[i] = 0;
    __syncthreads();
    for (int e = blockIdx.x * blockDim.x + tid; e < nnz;
         e += gridDim.x * blockDim.x)
        atomicAdd(&h[rows[e] >> BSHIFT], 1);
    __syncthreads();
    for (int i = tid; i < NBUCK; i += 256)
        if (h[i]) atomicAdd(&bcnt[i], h[i]);
}

// ---------------------------------------------------------------------------
// single-block exclusive scan of bucket counts -> boff, bcur (NBUCK <= 2048)
// ---------------------------------------------------------------------------
__global__ __launch_bounds__(256) void k_bscan(const int* __restrict__ bcnt,
                                               int* __restrict__ boff,
                                               int* __restrict__ bcur,
                                               int n, int nnz) {
    __shared__ int sd[256];
    const int t = threadIdx.x;
    const int base = t * 8;
    int v[8], s = 0;
#pragma unroll
    for (int i = 0; i < 8; ++i) {
        int idx = base + i;
        v[i] = (idx < n) ? bcnt[idx] : 0;
        s += v[i];
    }
    sd[t] = s;
    __syncthreads();
#pragma unroll
    for (int o = 1; o < 256; o <<= 1) {
        int x = (t >= o) ? sd[t - o] : 0;
        __syncthreads();
        if (t >= o) sd[t] += x;
        __syncthreads();
    }
    int run = (t == 0) ? 0 : sd[t - 1];
#pragma unroll
    for (int i = 0; i < 8; ++i) {
        int idx = base + i;
        if (idx < n) { boff[idx] = run; bcur[idx] = run; }
        run += v[i];
    }
    if (t == 255) boff[n] = nnz;
}

// ---------------------------------------------------------------------------
// bin edges into bucket-contiguous packed records.
// record = { (row_local << 18) | col , bits(val) }  -- one 8B store per edge
// per-block run reservation -> writes land in contiguous runs.
// ---------------------------------------------------------------------------
__global__ __launch_bounds__(256) void k_binscatter(
        const int* __restrict__ rows, const int* __restrict__ cols,
        const float* __restrict__ vals, int* __restrict__ bcur,
        uint2* __restrict__ rec, int nnz) {
    __shared__ int hist[NBUCK];
    __shared__ int runs[NBUCK];
    const int tid = threadIdx.x;
    const int e0 = blockIdx.x * CHUNK;
    const int e1 = min(nnz, e0 + CHUNK);

    for (int i = tid; i < NBUCK; i += 256) hist[i] = 0;
    __syncthreads();
    // pass 1: count
    for (int e = e0 + tid; e < e1; e += 256)
        atomicAdd(&hist[rows[e] >> BSHIFT], 1);
    __syncthreads();
    // reserve runs
    for (int i = tid; i < NBUCK; i += 256)
        runs[i] = hist[i] ? atomicAdd(&bcur[i], hist[i]) : 0;
    __syncthreads();
    // reset hist -> local cursors
    for (int i = tid; i < NBUCK; i += 256) hist[i] = 0;
    __syncthreads();
    // pass 2: place
    for (int e = e0 + tid; e < e1; e += 256) {
        const int r = rows[e];
        const int b = r >> BSHIFT;
        const int pos = runs[b] + atomicAdd(&hist[b], 1);
        const unsigned key = ((unsigned)(r & (BROWS - 1)) << COLBITS) |
                             (unsigned)cols[e];
        rec[pos] = make_uint2(key, __float_as_uint(vals[e]));
    }
}

// ---------------------------------------------------------------------------
// per-bucket counting sort: rec (bucket-contiguous) -> srec (row-sorted CSR
// order) + off[row].  One block per bucket; int LDS atomics only.  Scattered
// stores confined to the bucket's ~9 KB window => L2 merges, no amplification.
// ---------------------------------------------------------------------------
__global__ __launch_bounds__(256) void k_bsort(
        const int* __restrict__ boff, const uint2* __restrict__ rec,
        uint2* __restrict__ srec, int* __restrict__ off, int nnz) {
    __shared__ int h[BROWS];
    __shared__ int sc[BROWS];
    __shared__ int cur[BROWS];
    const int b = blockIdx.x;
    const int tid = threadIdx.x;
    const int s = boff[b];
    const int e = boff[b + 1];

    if (tid < BROWS) h[tid] = 0;
    __syncthreads();
    for (int i = s + tid; i < e; i += 256)
        atomicAdd(&h[rec[i].x >> COLBITS], 1);
    __syncthreads();
    if (tid < BROWS) sc[tid] = h[tid];
    __syncthreads();
#pragma unroll
    for (int o = 1; o < BROWS; o <<= 1) {
        int x = 0;
        if (tid < BROWS && tid >= o) x = sc[tid - o];
        __syncthreads();
        if (tid < BROWS && tid >= o) sc[tid] += x;
        __syncthreads();
    }
    const int r0 = b * BROWS;
    if (tid < BROWS) {
        const int excl = sc[tid] - h[tid];      // exclusive scan
        cur[tid] = excl;
        const int r = r0 + tid;
        if (r < N_TOTAL) off[r] = s + excl;
    }
    __syncthreads();
    for (int i = s + tid; i < e; i += 256) {
        const uint2 u = rec[i];
        const int rl = u.x >> COLBITS;
        const int p = s + atomicAdd(&cur[rl], 1);
        srec[p] = u;
    }
    if (b == 0 && tid == 0) off[N_TOTAL] = nnz;
}

// ---------------------------------------------------------------------------
// CSR SpMM, one wave per row.  4-edges-in-parallel float4 gather:
//   g = lane>>4 selects the edge, q = lane&15 the float4 dim-quarter.
// One load instruction gathers 4 different x rows (1 KB).  Row-end butterfly
// reduction folds the 4 group partials; 16 lanes store the row as float4.
// MODE 0: gather ue/ie, write y
// MODE 1: gather xbuf,  write y
// MODE 2: gather xbuf,  write y + z1 + z2  (fused layer-sum for the mean)
// ---------------------------------------------------------------------------
template <int MODE>
__global__ __launch_bounds__(256) void k_spmm(
        const int* __restrict__ off, const uint2* __restrict__ srec,
        const float* __restrict__ ue, const float* __restrict__ ie,
        const float* __restrict__ xbuf,
        const float* __restrict__ z1, const float* __restrict__ z2,
        float* __restrict__ ybuf, int nrows) {
    const int lane = threadIdx.x & 63;
    const int g    = lane >> 4;
    const int q    = lane & 15;
    const int w0   = (blockIdx.x * blockDim.x + threadIdx.x) >> 6;
    const int nw   = (gridDim.x * blockDim.x) >> 6;

    for (int r0 = w0; r0 < nrows; r0 += nw) {
        const int r = __builtin_amdgcn_readfirstlane(r0);
        const int s = off[r];
        const int e = off[r + 1];
        float ax = 0.f, ay = 0.f, az = 0.f, aw = 0.f;
        for (int base = s; base < e; base += 64) {
            const int nv = min(64, e - base);
            uint2 rv = make_uint2(0u, 0u);
            if (lane < nv) rv = srec[base + lane];   // zero-fill => branch-free tail
            int j = 0;
            for (; j + 8 <= nv; j += 8) {
                const unsigned k0 = __shfl(rv.x, j + g);
                const unsigned m0 = __shfl(rv.y, j + g);
                const unsigned k1 = __shfl(rv.x, j + 4 + g);
                const unsigned m1 = __shfl(rv.y, j + 4 + g);
                const int c0 = (int)(k0 & COLMASK);
                const int c1 = (int)(k1 & COLMASK);
                const float4 *p0, *p1;
                if (MODE == 0) {
                    p0 = (c0 < NUM_USER) ? (const float4*)ue + (size_t)c0 * 16
                                         : (const float4*)ie + (size_t)(c0 - NUM_USER) * 16;
                    p1 = (c1 < NUM_USER) ? (const float4*)ue + (size_t)c1 * 16
                                         : (const float4*)ie + (size_t)(c1 - NUM_USER) * 16;
                } else {
                    p0 = (const float4*)xbuf + (size_t)c0 * 16;
                    p1 = (const float4*)xbuf + (size_t)c1 * 16;
                }
                const float4 x0 = p0[q];
                const float4 x1 = p1[q];
                const float v0 = __uint_as_float(m0);
                const float v1 = __uint_as_float(m1);
                ax = fmaf(v0, x0.x, ax); ay = fmaf(v0, x0.y, ay);
                az = fmaf(v0, x0.z, az); aw = fmaf(v0, x0.w, aw);
                ax = fmaf(v1, x1.x, ax); ay = fmaf(v1, x1.y, ay);
                az = fmaf(v1, x1.z, az); aw = fmaf(v1, x1.w, aw);
            }
            for (; j < nv; j += 4) {
                const unsigned k0 = __shfl(rv.x, j + g);
                const unsigned m0 = __shfl(rv.y, j + g);
                const int c0 = (int)(k0 & COLMASK);
                const float4* p0;
                if (MODE == 0) {
                    p0 = (c0 < NUM_USER) ? (const float4*)ue + (size_t)c0 * 16
                                         : (const float4*)ie + (size_t)(c0 - NUM_USER) * 16;
                } else {
                    p0 = (const float4*)xbuf + (size_t)c0 * 16;
                }
                const float4 x0 = p0[q];
                const float v0 = __uint_as_float(m0);
                ax = fmaf(v0, x0.x, ax); ay = fmaf(v0, x0.y, ay);
                az = fmaf(v0, x0.z, az); aw = fmaf(v0, x0.w, aw);
            }
        }
        // fold the 4 edge-group partials (xor-16, xor-32 butterfly)
        ax += __shfl_xor(ax, 16); ay += __shfl_xor(ay, 16);
        az += __shfl_xor(az, 16); aw += __shfl_xor(aw, 16);
        ax += __shfl_xor(ax, 32); ay += __shfl_xor(ay, 32);
        az += __shfl_xor(az, 32); aw += __shfl_xor(aw, 32);
        if (lane < 16) {
            float4 o4 = make_float4(ax, ay, az, aw);
            const size_t o = (size_t)r * 16 + q;
            if (MODE == 2) {
                const float4 a1 = ((const float4*)z1)[o];
                const float4 a2 = ((const float4*)z2)[o];
                o4.x += a1.x + a2.x; o4.y += a1.y + a2.y;
                o4.z += a1.z + a2.z; o4.w += a1.w + a2.w;
            }
            ((float4*)ybuf)[o] = o4;
        }
    }
}

// ---------------------------------------------------------------------------
// final: mean = acc/3; logstd = mean @ W + b; std = exp; views.
// W column held in 64 VGPRs; row broadcast via v_readlane (no LDS inner loop).
// ---------------------------------------------------------------------------
__global__ __launch_bounds__(256) void k_final(
        float* __restrict__ mean_io,
        const float* __restrict__ W, const float* __restrict__ bias,
        const float* __restrict__ n1, const float* __restrict__ n2,
        float* __restrict__ std_out, float* __restrict__ v1,
        float* __restrict__ v2, int nrows) {
    const int   lane = threadIdx.x & 63;
    const float bj   = bias[lane];
    const int   w0   = (blockIdx.x * blockDim.x + threadIdx.x) >> 6;
    const int   nw   = (gridDim.x * blockDim.x) >> 6;

    float wreg[64];
#pragma unroll
    for (int k = 0; k < 64; ++k) wreg[k] = W[k * 64 + lane];

    for (int r = w0; r < nrows; r += nw) {
        const size_t base = (size_t)r * D;
        const float m = mean_io[base + lane] * (1.f / 3.f);
        float s = bj;
#pragma unroll
        for (int k = 0; k < 64; ++k) {
            const float mk = __uint_as_float(
                __builtin_amdgcn_readlane(__float_as_uint(m), k));
            s = fmaf(mk, wreg[k], s);
        }
        const float sd = __expf(s);
        mean_io[base + lane] = m;
        std_out[base + lane] = sd;
        v1[base + lane] = fmaf(sd * SCALE, n1[base + lane], m);
        v2[base + lane] = fmaf(sd * SCALE, n2[base + lane], m);
    }
}

// ---------------------------------------------------------------------------
extern "C" void kernel_launch(void* const* d_in, const int* in_sizes, int n_in,
                              void* d_out, int out_size, void* d_ws, size_t ws_size,
                              hipStream_t stream) {
    const float* ue   = (const float*)d_in[0];
    const float* ie   = (const float*)d_in[1];
    const float* W    = (const float*)d_in[2];
    const float* bias = (const float*)d_in[3];
    const int*   rows = (const int*)d_in[4];
    const int*   cols = (const int*)d_in[5];
    const float* vals = (const float*)d_in[6];
    const float* n1   = (const float*)d_in[7];
    const float* n2   = (const float*)d_in[8];
    const int    nnz  = in_sizes[4];

    float* out = (float*)d_out;
    const size_t ND = (size_t)N_TOTAL * D;

    // d_out layout: [mean | std | view1 | view2]
    // std segment doubles as binning scratch until k_final; view segs = ego ping-pong.
    float* acc  = out;            // mean segment: y1+y2+y3 (written by MODE 2) -> mean
    float* stdo = out + ND;       // std segment: scratch now, std at end
    float* y1   = out + 2 * ND;   // view1 segment: ego after layer 1
    float* y2   = out + 3 * ND;   // view2 segment: ego after layer 2

    // scratch carved from std segment (~33 MB of 57.6 MB)
    int*   ws   = (int*)stdo;
    int*   bcnt = ws;                          // NBUCK
    int*   boff = ws + 2048;                   // NBUCK+1
    int*   bcur = ws + 4096;                   // NBUCK
    int*   off  = ws + 6144;                   // N_TOTAL+1 (ends 231145)
    uint2* srec = (uint2*)(ws + 231424);       // nnz sorted records (16 MB)
    uint2* rec  = (uint2*)(ws + 4231424);      // nnz bucket-binned records (16 MB)

    const int nb2 = (nnz + CHUNK - 1) / CHUNK;

    // --- two-level CSR build: bucket-bin (coalesced) then in-bucket sort ---
    k_zero<<<7, 256, 0, stream>>>(bcnt, NBUCK);
    k_binhist<<<256, 256, 0, stream>>>(rows, bcnt, nnz);
    k_bscan<<<1, 256, 0, stream>>>(bcnt, boff, bcur, NBUCK, nnz);
    k_binscatter<<<nb2, 256, 0, stream>>>(rows, cols, vals, bcur, rec, nnz);
    k_bsort<<<NBUCK, 256, 0, stream>>>(boff, rec, srec, off, nnz);

    // --- 3 GCN layers, row-per-wave, float4 quad-edge gather ---
    k_spmm<0><<<2048, 256, 0, stream>>>(off, srec, ue, ie, nullptr,
                                        nullptr, nullptr, y1, N_TOTAL);
    k_spmm<1><<<2048, 256, 0, stream>>>(off, srec, nullptr, nullptr, y1,
                                        nullptr, nullptr, y2, N_TOTAL);
    k_spmm<2><<<2048, 256, 0, stream>>>(off, srec, nullptr, nullptr, y2,
                                        y1, y2, acc, N_TOTAL);

    // --- epilogue (overwrites all four output segments) ---
    k_final<<<2048, 256, 0, stream>>>(acc, W, bias, n1, n2,
                                      stdo, y1, y2, N_TOTAL);
}